// Round 2
// 280.335 us; speedup vs baseline: 1.0334x; 1.0334x over previous
//
#include <hip/hip_runtime.h>
#include <hip/hip_bf16.h>
#include <math.h>

#define Bn 8
#define Nn 2048
#define Dn 256

typedef short short8 __attribute__((ext_vector_type(8)));
typedef float floatx4 __attribute__((ext_vector_type(4)));

__device__ __forceinline__ short f2bf_bits(float f) {
    __bf16 h = (__bf16)f;
    return __builtin_bit_cast(short, h);
}

__device__ __forceinline__ float bf2f(short s) {
    unsigned u = ((unsigned)(unsigned short)s) << 16;
    return __builtin_bit_cast(float, u);
}

__device__ __forceinline__ void gl_lds16(const void* gsrc, void* ldst) {
    __builtin_amdgcn_global_load_lds(
        (const __attribute__((address_space(1))) void*)gsrc,
        (__attribute__((address_space(3))) void*)ldst, 16, 0, 0);
}

__device__ __forceinline__ float sigmoidf_(float z) {
    return 1.0f / (1.0f + __expf(-z));
}

// ---- Wt[e][d] = bf16(W_fp[d][e]) ------------------------------------------

__global__ void k_transpose(const float* __restrict__ W, short* __restrict__ Wt) {
    int e = blockIdx.x, d = threadIdx.x;
    Wt[e * Dn + d] = f2bf_bits(W[d * Dn + e]);
}

// ---- K1: proj rows (64 x 256 per block) via MFMA; fused norm, xn, sdot,
//          and x column-sum partials (xpart) from the staged A tiles. --------

__global__ __launch_bounds__(256) void k_projxn(
    const float* __restrict__ x, const short* __restrict__ Wt,
    const float* __restrict__ b_fp, const float* __restrict__ w_s,
    short* __restrict__ xn, float* __restrict__ sdot, float* __restrict__ nrm,
    float* __restrict__ xpart) {
    __shared__ __align__(16) short As[64 * 64];    // 8 KB
    __shared__ __align__(16) short Bs[256 * 64];   // 32 KB
    __shared__ float xsumS[4 * 256];               // 4 KB  [wave][d]
    const int t = threadIdx.x;
    const int bm = blockIdx.x * 64;                // global row base in [0, B*N)
    const int lane = t & 63, wv = t >> 6;
    const int wm = wv * 16;                        // wave's 16-row slab
    const int l15 = lane & 15, q = lane >> 4;

    for (int i = t; i < 1024; i += 256) xsumS[i] = 0.f;

    floatx4 acc[16];
    #pragma unroll
    for (int j = 0; j < 16; ++j) acc[j] = (floatx4){0.f, 0.f, 0.f, 0.f};

    const int rA = t >> 2, cA = (t & 3) * 16;      // A staging map
    const int rB = t >> 3, cB = (t & 7) * 8;       // B staging map

    for (int k0 = 0; k0 < Dn; k0 += 64) {
        // A: 64x64 fp32 -> bf16
        const float* gp = x + (size_t)(bm + rA) * Dn + k0 + cA;
        float4 v0 = *(const float4*)gp;
        float4 v1 = *(const float4*)(gp + 4);
        float4 v2 = *(const float4*)(gp + 8);
        float4 v3 = *(const float4*)(gp + 12);
        short8 o0, o1;
        o0[0] = f2bf_bits(v0.x); o0[1] = f2bf_bits(v0.y);
        o0[2] = f2bf_bits(v0.z); o0[3] = f2bf_bits(v0.w);
        o0[4] = f2bf_bits(v1.x); o0[5] = f2bf_bits(v1.y);
        o0[6] = f2bf_bits(v1.z); o0[7] = f2bf_bits(v1.w);
        o1[0] = f2bf_bits(v2.x); o1[1] = f2bf_bits(v2.y);
        o1[2] = f2bf_bits(v2.z); o1[3] = f2bf_bits(v2.w);
        o1[4] = f2bf_bits(v3.x); o1[5] = f2bf_bits(v3.y);
        o1[6] = f2bf_bits(v3.z); o1[7] = f2bf_bits(v3.w);
        *(short8*)(As + rA * 64 + cA) = o0;
        *(short8*)(As + rA * 64 + cA + 8) = o1;
        // B: Wt slice 256x64 via async global->LDS
        #pragma unroll
        for (int cc = 0; cc < 8; ++cc)
            gl_lds16(Wt + (size_t)(cc * 32 + rB) * Dn + k0 + cB,
                     Bs + (cc * 32 + rB) * 64 + cB);
        __syncthreads();
        #pragma unroll
        for (int ks = 0; ks < 2; ++ks) {
            short8 af = *(const short8*)(As + (wm + l15) * 64 + ks * 32 + q * 8);
            #pragma unroll
            for (int j = 0; j < 16; ++j) {
                short8 bfr = *(const short8*)(Bs + (j * 16 + l15) * 64 + ks * 32 + q * 8);
                acc[j] = __builtin_amdgcn_mfma_f32_16x16x32_bf16(af, bfr, acc[j], 0, 0, 0);
            }
        }
        // fused x column-sum: wave wv sums its 16 rows for column `lane`
        {
            float s = 0.f;
            #pragma unroll
            for (int r = 0; r < 16; ++r)
                s += bf2f(As[(wm + r) * 64 + lane]);
            xsumS[wv * 256 + k0 + lane] += s;
        }
        __syncthreads();
    }
    // xpart fold (all waves' partials visible after last sync)
    {
        float xs = xsumS[t] + xsumS[256 + t] + xsumS[512 + t] + xsumS[768 + t];
        xpart[(size_t)blockIdx.x * Dn + t] = xs;
    }
    // epilogue: per reg, one full row per 16-lane group
    float bfv[16], wsv[16];
    #pragma unroll
    for (int j = 0; j < 16; ++j) {
        bfv[j] = b_fp[j * 16 + l15];
        wsv[j] = w_s[j * 16 + l15];
    }
    #pragma unroll
    for (int reg = 0; reg < 4; ++reg) {
        int row = bm + wm + q * 4 + reg;
        float v[16];
        float pw = 0.f, pn = 0.f;
        #pragma unroll
        for (int j = 0; j < 16; ++j) {
            v[j] = acc[j][reg] + bfv[j];
            pw += v[j] * wsv[j];
            pn += v[j] * v[j];
        }
        #pragma unroll
        for (int m = 1; m < 16; m <<= 1) {
            pw += __shfl_xor(pw, m);
            pn += __shfl_xor(pn, m);
        }
        float nc = fmaxf(sqrtf(pn), 1e-12f);
        float inv = 1.0f / nc;
        size_t rbase = (size_t)row * Dn + l15;
        #pragma unroll
        for (int j = 0; j < 16; ++j)
            xn[rbase + j * 16] = f2bf_bits(v[j] * inv);
        if (l15 == 0) {
            sdot[row] = pw;
            nrm[row] = nc;
        }
    }
}

// ---- K2: sim = xn@xn^T, scaler/clamp, adj write (float4), per-tile degree.
//          Swapped MFMA operands: per-thread regs span 4 consecutive COLUMNS
//          of one row -> float4 stores. XCD swizzle: lin%8 -> batch, so each
//          XCD's xn working set is 1 MB (L2-resident). ----------------------

__global__ __launch_bounds__(256) void k_sim(
    const short* __restrict__ xn, const float* __restrict__ sdot,
    const float* __restrict__ b_s, float* __restrict__ adj,
    float* __restrict__ deg_part) {
    __shared__ __align__(16) short As[128 * 64];
    __shared__ __align__(16) short Bs[128 * 64];
    __shared__ float degS[2][128];
    const int t = threadIdx.x;
    int lin = (blockIdx.z * 16 + blockIdx.y) * 16 + blockIdx.x;   // 0..2047
    const int b = lin & 7;           // batch == XCD (round-robin heuristic)
    const int pos = lin >> 3;        // 0..255 tile within batch
    const int by = pos >> 4, cx = pos & 15;
    const int bn = cx * 128;         // col tile
    const int bm = by * 128;         // row tile
    const int lane = t & 63, wv = t >> 6;
    const int wm = (wv >> 1) * 64, wn = (wv & 1) * 64;
    const int l15 = lane & 15, q4 = lane >> 4;
    const int rr = t >> 3, c8 = (t & 7) * 8;
    const short* xb = xn + (size_t)b * Nn * Dn;

    floatx4 acc[4][4];
    #pragma unroll
    for (int i = 0; i < 4; ++i)
        #pragma unroll
        for (int j = 0; j < 4; ++j) acc[i][j] = (floatx4){0.f, 0.f, 0.f, 0.f};

    for (int k0 = 0; k0 < Dn; k0 += 64) {
        #pragma unroll
        for (int cc = 0; cc < 4; ++cc) {
            int r = cc * 32 + rr;
            gl_lds16(xb + (size_t)(bm + r) * Dn + k0 + c8, As + r * 64 + c8);
            gl_lds16(xb + (size_t)(bn + r) * Dn + k0 + c8, Bs + r * 64 + c8);
        }
        __syncthreads();
        #pragma unroll
        for (int ks = 0; ks < 2; ++ks) {
            short8 af[4], bfr[4];
            #pragma unroll
            for (int i = 0; i < 4; ++i)
                af[i] = *(const short8*)(As + (wm + i * 16 + l15) * 64 + ks * 32 + q4 * 8);
            #pragma unroll
            for (int j = 0; j < 4; ++j)
                bfr[j] = *(const short8*)(Bs + (wn + j * 16 + l15) * 64 + ks * 32 + q4 * 8);
            // SWAPPED operands: thread (l15,q4) reg holds
            // sim[bm+wm+i*16+l15][bn+wn+j*16+q4*4+reg] -> float4 stores
            #pragma unroll
            for (int i = 0; i < 4; ++i)
                #pragma unroll
                for (int j = 0; j < 4; ++j)
                    acc[i][j] = __builtin_amdgcn_mfma_f32_16x16x32_bf16(bfr[j], af[i], acc[i][j], 0, 0, 0);
        }
        __syncthreads();
    }
    // epilogue
    const float bsv = b_s[0];
    float srow[4];
    #pragma unroll
    for (int i = 0; i < 4; ++i)
        srow[i] = sigmoidf_(sdot[b * Nn + bm + wm + i * 16 + l15] + bsv);
    float scol[4][4];
    #pragma unroll
    for (int j = 0; j < 4; ++j)
        #pragma unroll
        for (int reg = 0; reg < 4; ++reg)
            scol[j][reg] = sigmoidf_(sdot[b * Nn + bn + wn + j * 16 + q4 * 4 + reg] + bsv);
    #pragma unroll
    for (int i = 0; i < 4; ++i) {
        float rs = 0.f;
        size_t rbase = ((size_t)b * Nn + (bm + wm + i * 16 + l15)) * Nn + bn + wn + q4 * 4;
        #pragma unroll
        for (int j = 0; j < 4; ++j) {
            float4 o;
            float sc;
            sc = fminf(fmaxf(0.5f * (srow[i] + scol[j][0]), 1e-6f), 1.0f);
            o.x = fmaxf(sc * acc[i][j][0], 1e-6f);
            sc = fminf(fmaxf(0.5f * (srow[i] + scol[j][1]), 1e-6f), 1.0f);
            o.y = fmaxf(sc * acc[i][j][1], 1e-6f);
            sc = fminf(fmaxf(0.5f * (srow[i] + scol[j][2]), 1e-6f), 1.0f);
            o.z = fmaxf(sc * acc[i][j][2], 1e-6f);
            sc = fminf(fmaxf(0.5f * (srow[i] + scol[j][3]), 1e-6f), 1.0f);
            o.w = fmaxf(sc * acc[i][j][3], 1e-6f);
            *(float4*)(adj + rbase + (size_t)j * 16) = o;
            rs += o.x + o.y + o.z + o.w;
        }
        // reduce across the 4 col-quad groups holding the same row
        rs += __shfl_xor(rs, 16);
        rs += __shfl_xor(rs, 32);
        if (q4 == 0) degS[wv & 1][wm + i * 16 + l15] = rs;
    }
    __syncthreads();
    if (t < 128)
        deg_part[((size_t)(b * 16 + cx)) * Nn + bm + t] = degS[0][t] + degS[1][t];
}

// ---- K3: colsum chunk (no atomics) + fused gpre partial ---------------------
// block (b, ck): cols ck*64..+63, all 2048 rows; 512 threads.
// gpart[b][ck][d] = sum_{m in chunk} cs[m]*nrm[m]*xn[m,d]  (proj = nrm*xn)

__global__ __launch_bounds__(512) void k_colsum(
    const float* __restrict__ adj, const float* __restrict__ deg_part,
    const short* __restrict__ xn, const float* __restrict__ nrm,
    float* __restrict__ gpart) {
    int b = blockIdx.x, ck = blockIdx.y, t = threadIdx.x;
    __shared__ float invdeg[Nn];        // 8 KB
    __shared__ float part[32][64];      // 8 KB
    __shared__ float csL[64];
    __shared__ float gHalf[2][Dn];      // 2 KB
    #pragma unroll
    for (int rc = 0; rc < 4; ++rc) {
        int row = rc * 512 + t;
        float s = 0.f;
        #pragma unroll
        for (int cx = 0; cx < 16; ++cx)
            s += deg_part[((size_t)(b * 16 + cx)) * Nn + row];
        invdeg[row] = 1.0f / fmaxf(s, 1e-6f);
    }
    __syncthreads();
    const int lc = (t & 15) * 4;        // col offset within 64
    const int rg = t >> 4;              // 0..31 row-group
    const int c0 = ck * 64;
    float sx = 0.f, sy = 0.f, sz = 0.f, sw = 0.f;
    for (int r = rg; r < Nn; r += 32) {
        float4 v = *(const float4*)(adj + ((size_t)b * Nn + r) * Nn + c0 + lc);
        float w = invdeg[r];
        sx += v.x * w; sy += v.y * w; sz += v.z * w; sw += v.w * w;
    }
    part[rg][lc + 0] = sx; part[rg][lc + 1] = sy;
    part[rg][lc + 2] = sz; part[rg][lc + 3] = sw;
    __syncthreads();
    if (t < 64) {
        float s = 0.f;
        #pragma unroll
        for (int g = 0; g < 32; ++g) s += part[g][t];
        csL[t] = s * nrm[b * Nn + c0 + t];   // fold proj = nrm * xn
    }
    __syncthreads();
    {
        int h = t >> 8, d = t & 255;    // all 512 threads: 2 halves x 32 m's
        float g = 0.f;
        #pragma unroll 4
        for (int mi = 0; mi < 32; ++mi) {
            int m = h * 32 + mi;
            g += csL[m] * bf2f(xn[((size_t)(b * Nn + c0 + m)) * Dn + d]);
        }
        gHalf[h][d] = g;
    }
    __syncthreads();
    if (t < Dn)
        gpart[(b * 32 + ck) * Dn + t] = gHalf[0][t] + gHalf[1][t];
}

// ---- K4: reduce partials -> matvecs -> LayerNorm -> out --------------------

__global__ __launch_bounds__(256) void k_final2(
    const float* __restrict__ gpart, const float* __restrict__ xpart,
    const float* __restrict__ W_rp, const float* __restrict__ b_rp,
    const float* __restrict__ W_gp, const float* __restrict__ b_gp,
    const float* __restrict__ gamma, const float* __restrict__ beta,
    float* __restrict__ out) {
    int b = blockIdx.x, t = threadIdx.x;
    __shared__ float gp_s[Dn];
    __shared__ float g1_s[Dn];
    __shared__ float red[8];
    float gs = 0.f, xs = 0.f;
    #pragma unroll
    for (int ck = 0; ck < 32; ++ck) {
        gs += gpart[(b * 32 + ck) * Dn + t];
        xs += xpart[(b * 32 + ck) * Dn + t];
    }
    gp_s[t] = gs * (1.0f / Nn);
    float xm = xs * (1.0f / Nn);
    __syncthreads();
    float g1 = b_rp[t];
    #pragma unroll 4
    for (int d = 0; d < Dn; ++d) g1 += gp_s[d] * W_rp[d * Dn + t];
    g1_s[t] = g1;
    __syncthreads();
    float g2 = b_gp[t];
    #pragma unroll 4
    for (int e = 0; e < Dn; ++e) g2 += g1_s[e] * W_gp[e * Dn + t];
    float h = g2 + xm;
    float sum = h;
    #pragma unroll
    for (int m = 1; m < 64; m <<= 1) sum += __shfl_xor(sum, m);
    if ((t & 63) == 0) red[t >> 6] = sum;
    __syncthreads();
    float mu = (red[0] + red[1] + red[2] + red[3]) * (1.0f / Dn);
    float dv = h - mu;
    float s2 = dv * dv;
    #pragma unroll
    for (int m = 1; m < 64; m <<= 1) s2 += __shfl_xor(s2, m);
    if ((t & 63) == 0) red[4 + (t >> 6)] = s2;
    __syncthreads();
    float var = (red[4] + red[5] + red[6] + red[7]) * (1.0f / Dn);
    out[b * Dn + t] = dv * rsqrtf(var + 1e-5f) * gamma[t] + beta[t];
}

// ---- launcher --------------------------------------------------------------

extern "C" void kernel_launch(void* const* d_in, const int* in_sizes, int n_in,
                              void* d_out, int out_size, void* d_ws, size_t ws_size,
                              hipStream_t stream) {
    const float* x     = (const float*)d_in[0];
    const float* W_fp  = (const float*)d_in[1];
    const float* b_fp  = (const float*)d_in[2];
    const float* w_s   = (const float*)d_in[3];
    const float* b_s   = (const float*)d_in[4];
    const float* W_rp  = (const float*)d_in[5];
    const float* b_rp  = (const float*)d_in[6];
    const float* W_gp  = (const float*)d_in[7];
    const float* b_gp  = (const float*)d_in[8];
    const float* gamma = (const float*)d_in[9];
    const float* beta  = (const float*)d_in[10];

    float* out = (float*)d_out;
    float* adj = out + Bn * Dn;   // outputs concatenated: out (B*D) then adj (B*N*N)

    char* ws = (char*)d_ws;
    short* xn    = (short*)(ws);                 // 8 MB
    short* Wt    = (short*)(ws + 8388608);       // 128 KB
    float* sdot  = (float*)(ws + 8519680);       // 64 KB
    float* nrm   = (float*)(ws + 8585216);       // 64 KB
    float* degp  = (float*)(ws + 8650752);       // 1 MB
    float* gpart = (float*)(ws + 9699328);       // 256 KB
    float* xpart = (float*)(ws + 9961472);       // 256 KB

    k_transpose<<<Dn, Dn, 0, stream>>>(W_fp, Wt);
    k_projxn<<<(Bn * Nn) / 64, 256, 0, stream>>>(x, Wt, b_fp, w_s, xn, sdot, nrm, xpart);
    k_sim<<<dim3(Nn / 128, Nn / 128, Bn), 256, 0, stream>>>(xn, sdot, b_s, adj, degp);
    k_colsum<<<dim3(Bn, 32), 512, 0, stream>>>(adj, degp, xn, nrm, gpart);
    k_final2<<<Bn, 256, 0, stream>>>(gpart, xpart, W_rp, b_rp, W_gp, b_gp, gamma, beta, out);
}

// Round 3
// 238.421 us; speedup vs baseline: 1.2151x; 1.1758x over previous
//
#include <hip/hip_runtime.h>
#include <hip/hip_bf16.h>
#include <math.h>

#define Bn 8
#define Nn 2048
#define Dn 256

typedef short short8 __attribute__((ext_vector_type(8)));
typedef float floatx4 __attribute__((ext_vector_type(4)));

__device__ __forceinline__ short f2bf_bits(float f) {
    __bf16 h = (__bf16)f;
    return __builtin_bit_cast(short, h);
}

__device__ __forceinline__ float bf2f(short s) {
    unsigned u = ((unsigned)(unsigned short)s) << 16;
    return __builtin_bit_cast(float, u);
}

__device__ __forceinline__ void gl_lds16(const void* gsrc, void* ldst) {
    __builtin_amdgcn_global_load_lds(
        (const __attribute__((address_space(1))) void*)gsrc,
        (__attribute__((address_space(3))) void*)ldst, 16, 0, 0);
}

__device__ __forceinline__ float sigmoidf_(float z) {
    return 1.0f / (1.0f + __expf(-z));
}

// ---- Wt[e][d] = bf16(W_fp[d][e]) — tiled, coalesced both sides -------------

__global__ __launch_bounds__(256) void k_transpose(const float* __restrict__ W,
                                                   short* __restrict__ Wt) {
    __shared__ float Ts[64][65];
    const int t = threadIdx.x;
    const int dt0 = blockIdx.x * 64, et0 = blockIdx.y * 64;
    const int ro = t >> 4, co = (t & 15) * 4;
    #pragma unroll
    for (int rr = 0; rr < 4; ++rr) {
        int row = rr * 16 + ro;
        float4 v = *(const float4*)(W + (size_t)(dt0 + row) * Dn + et0 + co);
        Ts[row][co + 0] = v.x; Ts[row][co + 1] = v.y;
        Ts[row][co + 2] = v.z; Ts[row][co + 3] = v.w;
    }
    __syncthreads();
    const int e = t >> 2, cd0 = (t & 3) * 16;
    short8 a, b;
    #pragma unroll
    for (int i = 0; i < 8; ++i) {
        a[i] = f2bf_bits(Ts[cd0 + i][e]);
        b[i] = f2bf_bits(Ts[cd0 + 8 + i][e]);
    }
    *(short8*)(Wt + (size_t)(et0 + e) * Dn + dt0 + cd0) = a;
    *(short8*)(Wt + (size_t)(et0 + e) * Dn + dt0 + cd0 + 8) = b;
}

// ---- K1: proj rows (64 x 256 per block) via MFMA; fused norm, xn, sdot,
//          x column-sum partials. 512 threads: 8 waves = 4 row-slabs x 2
//          column halves; cross-wave norm/sdot reduce via LDS. --------------

__global__ __launch_bounds__(512) void k_projxn(
    const float* __restrict__ x, const short* __restrict__ Wt,
    const float* __restrict__ b_fp, const float* __restrict__ w_s,
    short* __restrict__ xn, float* __restrict__ sdot, float* __restrict__ nrm,
    float* __restrict__ xpart) {
    __shared__ __align__(16) short As[64 * 64];    // 8 KB
    __shared__ __align__(16) short Bs[256 * 64];   // 32 KB
    __shared__ float xsumS[8 * 256];               // 8 KB  [wave][d]
    __shared__ float redW[2][64];                  // [jh][local row]
    __shared__ float redN[2][64];
    const int t = threadIdx.x;
    const int bm = blockIdx.x * 64;                // global row base in [0, B*N)
    const int lane = t & 63, wv = t >> 6;
    const int wm = (wv & 3) * 16;                  // wave's 16-row slab
    const int jh = wv >> 2;                        // wave's 128-col half
    const int l15 = lane & 15, q = lane >> 4;

    for (int i = t; i < 2048; i += 512) xsumS[i] = 0.f;

    floatx4 acc[8];
    #pragma unroll
    for (int j = 0; j < 8; ++j) acc[j] = (floatx4){0.f, 0.f, 0.f, 0.f};

    const int rA = t >> 3, cA = (t & 7) * 8;       // A staging map (64x64, 8/thr)
    const int rB = t >> 3, cB = (t & 7) * 8;       // B staging map

    for (int k0 = 0; k0 < Dn; k0 += 64) {
        // A: 64x64 fp32 -> bf16 (8 floats/thread)
        const float* gp = x + (size_t)(bm + rA) * Dn + k0 + cA;
        float4 v0 = *(const float4*)gp;
        float4 v1 = *(const float4*)(gp + 4);
        short8 o0;
        o0[0] = f2bf_bits(v0.x); o0[1] = f2bf_bits(v0.y);
        o0[2] = f2bf_bits(v0.z); o0[3] = f2bf_bits(v0.w);
        o0[4] = f2bf_bits(v1.x); o0[5] = f2bf_bits(v1.y);
        o0[6] = f2bf_bits(v1.z); o0[7] = f2bf_bits(v1.w);
        *(short8*)(As + rA * 64 + cA) = o0;
        // B: Wt slice 256x64 via async global->LDS (4 chunks/thread)
        #pragma unroll
        for (int cc = 0; cc < 4; ++cc)
            gl_lds16(Wt + (size_t)(cc * 64 + rB) * Dn + k0 + cB,
                     Bs + (cc * 64 + rB) * 64 + cB);
        __syncthreads();
        #pragma unroll
        for (int ks = 0; ks < 2; ++ks) {
            short8 af = *(const short8*)(As + (wm + l15) * 64 + ks * 32 + q * 8);
            #pragma unroll
            for (int jj = 0; jj < 8; ++jj) {
                short8 bfr = *(const short8*)(Bs + (jh * 128 + jj * 16 + l15) * 64 + ks * 32 + q * 8);
                acc[jj] = __builtin_amdgcn_mfma_f32_16x16x32_bf16(af, bfr, acc[jj], 0, 0, 0);
            }
        }
        // fused x column-sum: wave wv sums its 8 rows for column `lane`
        {
            float s = 0.f;
            #pragma unroll
            for (int r = 0; r < 8; ++r)
                s += bf2f(As[(wv * 8 + r) * 64 + lane]);
            xsumS[wv * 256 + k0 + lane] += s;
        }
        __syncthreads();
    }
    // xpart fold (all waves' partials visible after last sync)
    if (t < 256) {
        float xs = 0.f;
        #pragma unroll
        for (int w = 0; w < 8; ++w) xs += xsumS[w * 256 + t];
        xpart[(size_t)blockIdx.x * Dn + t] = xs;
    }
    // epilogue: wave covers 16 rows x its 128-col half (8 frags)
    float bfv[8], wsv[8];
    #pragma unroll
    for (int jj = 0; jj < 8; ++jj) {
        bfv[jj] = b_fp[jh * 128 + jj * 16 + l15];
        wsv[jj] = w_s[jh * 128 + jj * 16 + l15];
    }
    float vv[4][8];
    #pragma unroll
    for (int reg = 0; reg < 4; ++reg) {
        float pw = 0.f, pn = 0.f;
        #pragma unroll
        for (int jj = 0; jj < 8; ++jj) {
            float v = acc[jj][reg] + bfv[jj];
            vv[reg][jj] = v;
            pw += v * wsv[jj];
            pn += v * v;
        }
        #pragma unroll
        for (int m = 1; m < 16; m <<= 1) {
            pw += __shfl_xor(pw, m);
            pn += __shfl_xor(pn, m);
        }
        if (l15 == 0) {
            redW[jh][wm + q * 4 + reg] = pw;
            redN[jh][wm + q * 4 + reg] = pn;
        }
    }
    __syncthreads();
    #pragma unroll
    for (int reg = 0; reg < 4; ++reg) {
        int lr = wm + q * 4 + reg;
        float pw = redW[0][lr] + redW[1][lr];
        float pn = redN[0][lr] + redN[1][lr];
        float nc = fmaxf(sqrtf(pn), 1e-12f);
        float inv = 1.0f / nc;
        int row = bm + lr;
        size_t rbase = (size_t)row * Dn + jh * 128 + l15;
        #pragma unroll
        for (int jj = 0; jj < 8; ++jj)
            xn[rbase + jj * 16] = f2bf_bits(vv[reg][jj] * inv);
        if (jh == 0 && l15 == 0) {
            sdot[row] = pw;
            nrm[row] = nc;
        }
    }
}

// ---- K2: sim = xn@xn^T, scaler/clamp, adj write (float4), per-tile degree.
//          Swapped MFMA operands -> float4 stores. XCD swizzle: lin%8 ->
//          batch, so each XCD's xn working set is 1 MB (L2-resident). ------

__global__ __launch_bounds__(256) void k_sim(
    const short* __restrict__ xn, const float* __restrict__ sdot,
    const float* __restrict__ b_s, float* __restrict__ adj,
    float* __restrict__ deg_part) {
    __shared__ __align__(16) short As[128 * 64];
    __shared__ __align__(16) short Bs[128 * 64];
    __shared__ float degS[2][128];
    const int t = threadIdx.x;
    int lin = (blockIdx.z * 16 + blockIdx.y) * 16 + blockIdx.x;   // 0..2047
    const int b = lin & 7;           // batch == XCD (round-robin heuristic)
    const int pos = lin >> 3;        // 0..255 tile within batch
    const int by = pos >> 4, cx = pos & 15;
    const int bn = cx * 128;         // col tile
    const int bm = by * 128;         // row tile
    const int lane = t & 63, wv = t >> 6;
    const int wm = (wv >> 1) * 64, wn = (wv & 1) * 64;
    const int l15 = lane & 15, q4 = lane >> 4;
    const int rr = t >> 3, c8 = (t & 7) * 8;
    const short* xb = xn + (size_t)b * Nn * Dn;

    floatx4 acc[4][4];
    #pragma unroll
    for (int i = 0; i < 4; ++i)
        #pragma unroll
        for (int j = 0; j < 4; ++j) acc[i][j] = (floatx4){0.f, 0.f, 0.f, 0.f};

    for (int k0 = 0; k0 < Dn; k0 += 64) {
        #pragma unroll
        for (int cc = 0; cc < 4; ++cc) {
            int r = cc * 32 + rr;
            gl_lds16(xb + (size_t)(bm + r) * Dn + k0 + c8, As + r * 64 + c8);
            gl_lds16(xb + (size_t)(bn + r) * Dn + k0 + c8, Bs + r * 64 + c8);
        }
        __syncthreads();
        #pragma unroll
        for (int ks = 0; ks < 2; ++ks) {
            short8 af[4], bfr[4];
            #pragma unroll
            for (int i = 0; i < 4; ++i)
                af[i] = *(const short8*)(As + (wm + i * 16 + l15) * 64 + ks * 32 + q4 * 8);
            #pragma unroll
            for (int j = 0; j < 4; ++j)
                bfr[j] = *(const short8*)(Bs + (wn + j * 16 + l15) * 64 + ks * 32 + q4 * 8);
            // SWAPPED operands: thread (l15,q4) reg holds
            // sim[bm+wm+i*16+l15][bn+wn+j*16+q4*4+reg] -> float4 stores
            #pragma unroll
            for (int i = 0; i < 4; ++i)
                #pragma unroll
                for (int j = 0; j < 4; ++j)
                    acc[i][j] = __builtin_amdgcn_mfma_f32_16x16x32_bf16(bfr[j], af[i], acc[i][j], 0, 0, 0);
        }
        __syncthreads();
    }
    // epilogue
    const float bsv = b_s[0];
    float srow[4];
    #pragma unroll
    for (int i = 0; i < 4; ++i)
        srow[i] = sigmoidf_(sdot[b * Nn + bm + wm + i * 16 + l15] + bsv);
    float scol[4][4];
    #pragma unroll
    for (int j = 0; j < 4; ++j)
        #pragma unroll
        for (int reg = 0; reg < 4; ++reg)
            scol[j][reg] = sigmoidf_(sdot[b * Nn + bn + wn + j * 16 + q4 * 4 + reg] + bsv);
    #pragma unroll
    for (int i = 0; i < 4; ++i) {
        float rs = 0.f;
        size_t rbase = ((size_t)b * Nn + (bm + wm + i * 16 + l15)) * Nn + bn + wn + q4 * 4;
        #pragma unroll
        for (int j = 0; j < 4; ++j) {
            float4 o;
            float sc;
            sc = fminf(fmaxf(0.5f * (srow[i] + scol[j][0]), 1e-6f), 1.0f);
            o.x = fmaxf(sc * acc[i][j][0], 1e-6f);
            sc = fminf(fmaxf(0.5f * (srow[i] + scol[j][1]), 1e-6f), 1.0f);
            o.y = fmaxf(sc * acc[i][j][1], 1e-6f);
            sc = fminf(fmaxf(0.5f * (srow[i] + scol[j][2]), 1e-6f), 1.0f);
            o.z = fmaxf(sc * acc[i][j][2], 1e-6f);
            sc = fminf(fmaxf(0.5f * (srow[i] + scol[j][3]), 1e-6f), 1.0f);
            o.w = fmaxf(sc * acc[i][j][3], 1e-6f);
            *(float4*)(adj + rbase + (size_t)j * 16) = o;
            rs += o.x + o.y + o.z + o.w;
        }
        // reduce across the 4 col-quad groups holding the same row
        rs += __shfl_xor(rs, 16);
        rs += __shfl_xor(rs, 32);
        if (q4 == 0) degS[wv & 1][wm + i * 16 + l15] = rs;
    }
    __syncthreads();
    if (t < 128)
        deg_part[((size_t)(b * 16 + cx)) * Nn + bm + t] = degS[0][t] + degS[1][t];
}

// ---- K3: colsum chunk (64 cols, 1024 threads -> 16 waves/CU) + fused gpre --
// gpart[b][ck][d] = sum_{m in chunk} cs[m]*nrm[m]*xn[m,d]  (proj = nrm*xn)

__global__ __launch_bounds__(1024) void k_colsum(
    const float* __restrict__ adj, const float* __restrict__ deg_part,
    const short* __restrict__ xn, const float* __restrict__ nrm,
    float* __restrict__ gpart) {
    int b = blockIdx.x, ck = blockIdx.y, t = threadIdx.x;
    __shared__ float invdeg[Nn];        // 8 KB
    __shared__ float part[64][64];      // 16 KB
    __shared__ float csL[64];
    __shared__ float gQ[4][Dn];         // 4 KB
    #pragma unroll
    for (int rc = 0; rc < 2; ++rc) {
        int row = rc * 1024 + t;
        float s = 0.f;
        #pragma unroll
        for (int cx = 0; cx < 16; ++cx)
            s += deg_part[((size_t)(b * 16 + cx)) * Nn + row];
        invdeg[row] = 1.0f / fmaxf(s, 1e-6f);
    }
    __syncthreads();
    const int lc = (t & 15) * 4;        // col offset within 64
    const int rg = t >> 4;              // 0..63 row-group
    const int c0 = ck * 64;
    float sx = 0.f, sy = 0.f, sz = 0.f, sw = 0.f;
    for (int r = rg; r < Nn; r += 64) {
        float4 v = *(const float4*)(adj + ((size_t)b * Nn + r) * Nn + c0 + lc);
        float w = invdeg[r];
        sx += v.x * w; sy += v.y * w; sz += v.z * w; sw += v.w * w;
    }
    part[rg][lc + 0] = sx; part[rg][lc + 1] = sy;
    part[rg][lc + 2] = sz; part[rg][lc + 3] = sw;
    __syncthreads();
    if (t < 64) {
        float s = 0.f;
        #pragma unroll
        for (int g = 0; g < 64; ++g) s += part[g][t];
        csL[t] = s * nrm[b * Nn + c0 + t];   // fold proj = nrm * xn
    }
    __syncthreads();
    {
        int h = t >> 8, d = t & 255;    // 4 quarters x 16 m's each
        float g = 0.f;
        #pragma unroll 4
        for (int mi = 0; mi < 16; ++mi) {
            int m = h * 16 + mi;
            g += csL[m] * bf2f(xn[((size_t)(b * Nn + c0 + m)) * Dn + d]);
        }
        gQ[h][d] = g;
    }
    __syncthreads();
    if (t < Dn)
        gpart[(b * 32 + ck) * Dn + t] = gQ[0][t] + gQ[1][t] + gQ[2][t] + gQ[3][t];
}

// ---- K4: reduce partials -> matvecs (4-way d-chunk parallel) -> LN -> out --

__global__ __launch_bounds__(1024) void k_final2(
    const float* __restrict__ gpart, const float* __restrict__ xpart,
    const float* __restrict__ W_rp, const float* __restrict__ b_rp,
    const float* __restrict__ W_gp, const float* __restrict__ b_gp,
    const float* __restrict__ gamma, const float* __restrict__ beta,
    float* __restrict__ out) {
    int b = blockIdx.x, t = threadIdx.x;
    const int d = t & 255, c4 = t >> 8;   // c4 in 0..3
    __shared__ float pS[4][Dn];           // partial buffer (reused)
    __shared__ float xS[4][Dn];
    __shared__ float gp_s[Dn];
    __shared__ float xm_s[Dn];
    __shared__ float g1_s[Dn];
    __shared__ float red[8];
    // fold gpart/xpart: each c4 sums 8 chunks
    {
        float gs = 0.f, xs = 0.f;
        #pragma unroll
        for (int k = 0; k < 8; ++k) {
            int ck = c4 * 8 + k;
            gs += gpart[(b * 32 + ck) * Dn + d];
            xs += xpart[(b * 32 + ck) * Dn + d];
        }
        pS[c4][d] = gs;
        xS[c4][d] = xs;
    }
    __syncthreads();
    if (t < Dn) {
        gp_s[t] = (pS[0][t] + pS[1][t] + pS[2][t] + pS[3][t]) * (1.0f / Nn);
        xm_s[t] = (xS[0][t] + xS[1][t] + xS[2][t] + xS[3][t]) * (1.0f / Nn);
    }
    __syncthreads();
    // matvec1: g1 = W_rp^T gp + b_rp, 4-way over d-chunks
    {
        float m1 = 0.f;
        #pragma unroll 4
        for (int i = 0; i < 64; ++i) {
            int dd = c4 * 64 + i;
            m1 += gp_s[dd] * W_rp[dd * Dn + d];
        }
        pS[c4][d] = m1;
    }
    __syncthreads();
    if (t < Dn) g1_s[t] = b_rp[t] + pS[0][t] + pS[1][t] + pS[2][t] + pS[3][t];
    __syncthreads();
    // matvec2: g2 = W_gp^T g1 + b_gp
    {
        float m2 = 0.f;
        #pragma unroll 4
        for (int i = 0; i < 64; ++i) {
            int ee = c4 * 64 + i;
            m2 += g1_s[ee] * W_gp[ee * Dn + d];
        }
        pS[c4][d] = m2;
    }
    __syncthreads();
    float h = 0.f;
    if (t < Dn) {
        h = b_gp[t] + pS[0][t] + pS[1][t] + pS[2][t] + pS[3][t] + xm_s[t];
        float sum = h;
        #pragma unroll
        for (int m = 1; m < 64; m <<= 1) sum += __shfl_xor(sum, m);
        if ((t & 63) == 0) red[t >> 6] = sum;
    }
    __syncthreads();
    float mu = (red[0] + red[1] + red[2] + red[3]) * (1.0f / Dn);
    if (t < Dn) {
        float dv = h - mu;
        float s2 = dv * dv;
        #pragma unroll
        for (int m = 1; m < 64; m <<= 1) s2 += __shfl_xor(s2, m);
        if ((t & 63) == 0) red[4 + (t >> 6)] = s2;
    }
    __syncthreads();
    if (t < Dn) {
        float dv = h - mu;
        float var = (red[4] + red[5] + red[6] + red[7]) * (1.0f / Dn);
        out[b * Dn + t] = dv * rsqrtf(var + 1e-5f) * gamma[t] + beta[t];
    }
}

// ---- launcher --------------------------------------------------------------

extern "C" void kernel_launch(void* const* d_in, const int* in_sizes, int n_in,
                              void* d_out, int out_size, void* d_ws, size_t ws_size,
                              hipStream_t stream) {
    const float* x     = (const float*)d_in[0];
    const float* W_fp  = (const float*)d_in[1];
    const float* b_fp  = (const float*)d_in[2];
    const float* w_s   = (const float*)d_in[3];
    const float* b_s   = (const float*)d_in[4];
    const float* W_rp  = (const float*)d_in[5];
    const float* b_rp  = (const float*)d_in[6];
    const float* W_gp  = (const float*)d_in[7];
    const float* b_gp  = (const float*)d_in[8];
    const float* gamma = (const float*)d_in[9];
    const float* beta  = (const float*)d_in[10];

    float* out = (float*)d_out;
    float* adj = out + Bn * Dn;   // outputs concatenated: out (B*D) then adj (B*N*N)

    char* ws = (char*)d_ws;
    short* xn    = (short*)(ws);                 // 8 MB
    short* Wt    = (short*)(ws + 8388608);       // 128 KB
    float* sdot  = (float*)(ws + 8519680);       // 64 KB
    float* nrm   = (float*)(ws + 8585216);       // 64 KB
    float* degp  = (float*)(ws + 8650752);       // 1 MB
    float* gpart = (float*)(ws + 9699328);       // 256 KB
    float* xpart = (float*)(ws + 9961472);       // 256 KB

    k_transpose<<<dim3(4, 4), 256, 0, stream>>>(W_fp, Wt);
    k_projxn<<<(Bn * Nn) / 64, 512, 0, stream>>>(x, Wt, b_fp, w_s, xn, sdot, nrm, xpart);
    k_sim<<<dim3(Nn / 128, Nn / 128, Bn), 256, 0, stream>>>(xn, sdot, b_s, adj, degp);
    k_colsum<<<dim3(Bn, 32), 1024, 0, stream>>>(adj, degp, xn, nrm, gpart);
    k_final2<<<Bn, 1024, 0, stream>>>(gpart, xpart, W_rp, b_rp, W_gp, b_gp, gamma, beta, out);
}

// Round 4
// 237.649 us; speedup vs baseline: 1.2190x; 1.0032x over previous
//
#include <hip/hip_runtime.h>
#include <hip/hip_bf16.h>
#include <math.h>

#define Bn 8
#define Nn 2048
#define Dn 256

typedef short short8 __attribute__((ext_vector_type(8)));
typedef float floatx4 __attribute__((ext_vector_type(4)));

__device__ __forceinline__ short f2bf_bits(float f) {
    __bf16 h = (__bf16)f;
    return __builtin_bit_cast(short, h);
}

__device__ __forceinline__ float bf2f(short s) {
    unsigned u = ((unsigned)(unsigned short)s) << 16;
    return __builtin_bit_cast(float, u);
}

__device__ __forceinline__ void gl_lds16(const void* gsrc, void* ldst) {
    __builtin_amdgcn_global_load_lds(
        (const __attribute__((address_space(1))) void*)gsrc,
        (__attribute__((address_space(3))) void*)ldst, 16, 0, 0);
}

__device__ __forceinline__ float sigmoidf_(float z) {
    return 1.0f / (1.0f + __expf(-z));
}

// ---- Wt[e][d] = bf16(W_fp[d][e]) — tiled, coalesced both sides -------------

__global__ __launch_bounds__(256) void k_transpose(const float* __restrict__ W,
                                                   short* __restrict__ Wt) {
    __shared__ float Ts[64][65];
    const int t = threadIdx.x;
    const int dt0 = blockIdx.x * 64, et0 = blockIdx.y * 64;
    const int ro = t >> 4, co = (t & 15) * 4;
    #pragma unroll
    for (int rr = 0; rr < 4; ++rr) {
        int row = rr * 16 + ro;
        float4 v = *(const float4*)(W + (size_t)(dt0 + row) * Dn + et0 + co);
        Ts[row][co + 0] = v.x; Ts[row][co + 1] = v.y;
        Ts[row][co + 2] = v.z; Ts[row][co + 3] = v.w;
    }
    __syncthreads();
    const int e = t >> 2, cd0 = (t & 3) * 16;
    short8 a, b;
    #pragma unroll
    for (int i = 0; i < 8; ++i) {
        a[i] = f2bf_bits(Ts[cd0 + i][e]);
        b[i] = f2bf_bits(Ts[cd0 + 8 + i][e]);
    }
    *(short8*)(Wt + (size_t)(et0 + e) * Dn + dt0 + cd0) = a;
    *(short8*)(Wt + (size_t)(et0 + e) * Dn + dt0 + cd0 + 8) = b;
}

// ---- K1: proj rows (64 x 256 per block) via MFMA; fused norm, xn, sdot,
//          x column-sum partials. 512 threads: 8 waves = 4 row-slabs x 2
//          column halves; cross-wave norm/sdot reduce via LDS. --------------

__global__ __launch_bounds__(512) void k_projxn(
    const float* __restrict__ x, const short* __restrict__ Wt,
    const float* __restrict__ b_fp, const float* __restrict__ w_s,
    short* __restrict__ xn, float* __restrict__ sdot, float* __restrict__ nrm,
    float* __restrict__ xpart) {
    __shared__ __align__(16) short As[64 * 64];    // 8 KB
    __shared__ __align__(16) short Bs[256 * 64];   // 32 KB
    __shared__ float xsumS[8 * 256];               // 8 KB  [wave][d]
    __shared__ float redW[2][64];                  // [jh][local row]
    __shared__ float redN[2][64];
    const int t = threadIdx.x;
    const int bm = blockIdx.x * 64;                // global row base in [0, B*N)
    const int lane = t & 63, wv = t >> 6;
    const int wm = (wv & 3) * 16;                  // wave's 16-row slab
    const int jh = wv >> 2;                        // wave's 128-col half
    const int l15 = lane & 15, q = lane >> 4;

    for (int i = t; i < 2048; i += 512) xsumS[i] = 0.f;

    floatx4 acc[8];
    #pragma unroll
    for (int j = 0; j < 8; ++j) acc[j] = (floatx4){0.f, 0.f, 0.f, 0.f};

    const int rA = t >> 3, cA = (t & 7) * 8;       // A staging map (64x64, 8/thr)
    const int rB = t >> 3, cB = (t & 7) * 8;       // B staging map

    for (int k0 = 0; k0 < Dn; k0 += 64) {
        // A: 64x64 fp32 -> bf16 (8 floats/thread)
        const float* gp = x + (size_t)(bm + rA) * Dn + k0 + cA;
        float4 v0 = *(const float4*)gp;
        float4 v1 = *(const float4*)(gp + 4);
        short8 o0;
        o0[0] = f2bf_bits(v0.x); o0[1] = f2bf_bits(v0.y);
        o0[2] = f2bf_bits(v0.z); o0[3] = f2bf_bits(v0.w);
        o0[4] = f2bf_bits(v1.x); o0[5] = f2bf_bits(v1.y);
        o0[6] = f2bf_bits(v1.z); o0[7] = f2bf_bits(v1.w);
        *(short8*)(As + rA * 64 + cA) = o0;
        // B: Wt slice 256x64 via async global->LDS (4 chunks/thread)
        #pragma unroll
        for (int cc = 0; cc < 4; ++cc)
            gl_lds16(Wt + (size_t)(cc * 64 + rB) * Dn + k0 + cB,
                     Bs + (cc * 64 + rB) * 64 + cB);
        __syncthreads();
        #pragma unroll
        for (int ks = 0; ks < 2; ++ks) {
            short8 af = *(const short8*)(As + (wm + l15) * 64 + ks * 32 + q * 8);
            #pragma unroll
            for (int jj = 0; jj < 8; ++jj) {
                short8 bfr = *(const short8*)(Bs + (jh * 128 + jj * 16 + l15) * 64 + ks * 32 + q * 8);
                acc[jj] = __builtin_amdgcn_mfma_f32_16x16x32_bf16(af, bfr, acc[jj], 0, 0, 0);
            }
        }
        // fused x column-sum: wave wv sums its 8 rows for column `lane`
        {
            float s = 0.f;
            #pragma unroll
            for (int r = 0; r < 8; ++r)
                s += bf2f(As[(wv * 8 + r) * 64 + lane]);
            xsumS[wv * 256 + k0 + lane] += s;
        }
        __syncthreads();
    }
    // xpart fold (all waves' partials visible after last sync)
    if (t < 256) {
        float xs = 0.f;
        #pragma unroll
        for (int w = 0; w < 8; ++w) xs += xsumS[w * 256 + t];
        xpart[(size_t)blockIdx.x * Dn + t] = xs;
    }
    // epilogue: wave covers 16 rows x its 128-col half (8 frags)
    float bfv[8], wsv[8];
    #pragma unroll
    for (int jj = 0; jj < 8; ++jj) {
        bfv[jj] = b_fp[jh * 128 + jj * 16 + l15];
        wsv[jj] = w_s[jh * 128 + jj * 16 + l15];
    }
    float vv[4][8];
    #pragma unroll
    for (int reg = 0; reg < 4; ++reg) {
        float pw = 0.f, pn = 0.f;
        #pragma unroll
        for (int jj = 0; jj < 8; ++jj) {
            float v = acc[jj][reg] + bfv[jj];
            vv[reg][jj] = v;
            pw += v * wsv[jj];
            pn += v * v;
        }
        #pragma unroll
        for (int m = 1; m < 16; m <<= 1) {
            pw += __shfl_xor(pw, m);
            pn += __shfl_xor(pn, m);
        }
        if (l15 == 0) {
            redW[jh][wm + q * 4 + reg] = pw;
            redN[jh][wm + q * 4 + reg] = pn;
        }
    }
    __syncthreads();
    #pragma unroll
    for (int reg = 0; reg < 4; ++reg) {
        int lr = wm + q * 4 + reg;
        float pw = redW[0][lr] + redW[1][lr];
        float pn = redN[0][lr] + redN[1][lr];
        float nc = fmaxf(sqrtf(pn), 1e-12f);
        float inv = 1.0f / nc;
        int row = bm + lr;
        size_t rbase = (size_t)row * Dn + jh * 128 + l15;
        #pragma unroll
        for (int jj = 0; jj < 8; ++jj)
            xn[rbase + jj * 16] = f2bf_bits(vv[reg][jj] * inv);
        if (jh == 0 && l15 == 0) {
            sdot[row] = pw;
            nrm[row] = nc;
        }
    }
}

// ---- K2: sim = xn@xn^T with 128x256 tiles (512 thr, 8 waves = 2x4 of 64x64).
//          Staged xn traffic: 1024 blocks x 48 KB x 4 = 196 MB (was 524 MB).
//          Swapped MFMA operands -> float4 stores. XCD swizzle: lin&7 ->
//          batch, each XCD's xn slice = 1 MB (L2-resident). ----------------

__global__ __launch_bounds__(512) void k_sim(
    const short* __restrict__ xn, const float* __restrict__ sdot,
    const float* __restrict__ b_s, float* __restrict__ adj,
    float* __restrict__ deg_part) {
    __shared__ __align__(16) short As[128 * 64];   // 16 KB
    __shared__ __align__(16) short Bs[256 * 64];   // 32 KB
    __shared__ float degS[4][128];                 // 2 KB
    const int t = threadIdx.x;
    int lin = (blockIdx.z * 16 + blockIdx.y) * 8 + blockIdx.x;    // 0..1023
    const int b = lin & 7;           // batch == XCD (round-robin heuristic)
    const int pos = lin >> 3;        // 0..127 tile within batch
    const int by = pos >> 3, cx = pos & 7;
    const int bm = by * 128;         // row tile (16 tiles)
    const int bn = cx * 256;         // col tile (8 tiles)
    const int lane = t & 63, wv = t >> 6;
    const int wm = (wv >> 2) * 64;   // {0,64}
    const int wn = (wv & 3) * 64;    // {0,64,128,192}
    const int l15 = lane & 15, q4 = lane >> 4;
    const int rr = t >> 3, c8 = (t & 7) * 8;
    const short* xb = xn + (size_t)b * Nn * Dn;

    floatx4 acc[4][4];
    #pragma unroll
    for (int i = 0; i < 4; ++i)
        #pragma unroll
        for (int j = 0; j < 4; ++j) acc[i][j] = (floatx4){0.f, 0.f, 0.f, 0.f};

    for (int k0 = 0; k0 < Dn; k0 += 64) {
        #pragma unroll
        for (int cc = 0; cc < 2; ++cc) {
            int r = cc * 64 + rr;
            gl_lds16(xb + (size_t)(bm + r) * Dn + k0 + c8, As + r * 64 + c8);
        }
        #pragma unroll
        for (int cc = 0; cc < 4; ++cc) {
            int r = cc * 64 + rr;
            gl_lds16(xb + (size_t)(bn + r) * Dn + k0 + c8, Bs + r * 64 + c8);
        }
        __syncthreads();
        #pragma unroll
        for (int ks = 0; ks < 2; ++ks) {
            short8 af[4], bfr[4];
            #pragma unroll
            for (int i = 0; i < 4; ++i)
                af[i] = *(const short8*)(As + (wm + i * 16 + l15) * 64 + ks * 32 + q4 * 8);
            #pragma unroll
            for (int j = 0; j < 4; ++j)
                bfr[j] = *(const short8*)(Bs + (wn + j * 16 + l15) * 64 + ks * 32 + q4 * 8);
            // SWAPPED operands: thread (l15,q4) reg holds
            // sim[bm+wm+i*16+l15][bn+wn+j*16+q4*4+reg] -> float4 stores
            #pragma unroll
            for (int i = 0; i < 4; ++i)
                #pragma unroll
                for (int j = 0; j < 4; ++j)
                    acc[i][j] = __builtin_amdgcn_mfma_f32_16x16x32_bf16(bfr[j], af[i], acc[i][j], 0, 0, 0);
        }
        __syncthreads();
    }
    // epilogue
    const float bsv = b_s[0];
    float srow[4];
    #pragma unroll
    for (int i = 0; i < 4; ++i)
        srow[i] = sigmoidf_(sdot[b * Nn + bm + wm + i * 16 + l15] + bsv);
    float scol[4][4];
    #pragma unroll
    for (int j = 0; j < 4; ++j)
        #pragma unroll
        for (int reg = 0; reg < 4; ++reg)
            scol[j][reg] = sigmoidf_(sdot[b * Nn + bn + wn + j * 16 + q4 * 4 + reg] + bsv);
    #pragma unroll
    for (int i = 0; i < 4; ++i) {
        float rs = 0.f;
        size_t rbase = ((size_t)b * Nn + (bm + wm + i * 16 + l15)) * Nn + bn + wn + q4 * 4;
        #pragma unroll
        for (int j = 0; j < 4; ++j) {
            float4 o;
            float sc;
            sc = fminf(fmaxf(0.5f * (srow[i] + scol[j][0]), 1e-6f), 1.0f);
            o.x = fmaxf(sc * acc[i][j][0], 1e-6f);
            sc = fminf(fmaxf(0.5f * (srow[i] + scol[j][1]), 1e-6f), 1.0f);
            o.y = fmaxf(sc * acc[i][j][1], 1e-6f);
            sc = fminf(fmaxf(0.5f * (srow[i] + scol[j][2]), 1e-6f), 1.0f);
            o.z = fmaxf(sc * acc[i][j][2], 1e-6f);
            sc = fminf(fmaxf(0.5f * (srow[i] + scol[j][3]), 1e-6f), 1.0f);
            o.w = fmaxf(sc * acc[i][j][3], 1e-6f);
            *(float4*)(adj + rbase + (size_t)j * 16) = o;
            rs += o.x + o.y + o.z + o.w;
        }
        // reduce across the 4 col-quad groups holding the same row
        rs += __shfl_xor(rs, 16);
        rs += __shfl_xor(rs, 32);
        if (q4 == 0) degS[wv & 3][wm + i * 16 + l15] = rs;
    }
    __syncthreads();
    if (t < 128)
        deg_part[((size_t)(b * 8 + cx)) * Nn + bm + t] =
            degS[0][t] + degS[1][t] + degS[2][t] + degS[3][t];
}

// ---- K2b: invdeg[b][r] = 1 / max(sum_cx deg_part, 1e-6) --------------------

__global__ __launch_bounds__(256) void k_deg(const float* __restrict__ deg_part,
                                             float* __restrict__ invdeg) {
    int b = blockIdx.x, t = blockIdx.y * 256 + threadIdx.x;
    float s = 0.f;
    #pragma unroll
    for (int cx = 0; cx < 8; ++cx)
        s += deg_part[((size_t)(b * 8 + cx)) * Nn + t];
    invdeg[b * Nn + t] = 1.0f / fmaxf(s, 1e-6f);
}

// ---- K3: colsum chunk (64 cols, 1024 threads) + fused gpre partial ---------
// gpart[b][ck][d] = sum_{m in chunk} cs[m]*nrm[m]*xn[m,d]  (proj = nrm*xn)

__global__ __launch_bounds__(1024) void k_colsum(
    const float* __restrict__ adj, const float* __restrict__ invdeg,
    const short* __restrict__ xn, const float* __restrict__ nrm,
    float* __restrict__ gpart) {
    int b = blockIdx.x, ck = blockIdx.y, t = threadIdx.x;
    __shared__ float invS[Nn];          // 8 KB
    __shared__ float part[64][64];      // 16 KB
    __shared__ float csL[64];
    __shared__ float gQ[4][Dn];         // 4 KB
    invS[t] = invdeg[b * Nn + t];
    invS[t + 1024] = invdeg[b * Nn + t + 1024];
    __syncthreads();
    const int lc = (t & 15) * 4;        // col offset within 64
    const int rg = t >> 4;              // 0..63 row-group
    const int c0 = ck * 64;
    float sx = 0.f, sy = 0.f, sz = 0.f, sw = 0.f;
    for (int r = rg; r < Nn; r += 64) {
        float4 v = *(const float4*)(adj + ((size_t)b * Nn + r) * Nn + c0 + lc);
        float w = invS[r];
        sx += v.x * w; sy += v.y * w; sz += v.z * w; sw += v.w * w;
    }
    part[rg][lc + 0] = sx; part[rg][lc + 1] = sy;
    part[rg][lc + 2] = sz; part[rg][lc + 3] = sw;
    __syncthreads();
    if (t < 64) {
        float s = 0.f;
        #pragma unroll
        for (int g = 0; g < 64; ++g) s += part[g][t];
        csL[t] = s * nrm[b * Nn + c0 + t];   // fold proj = nrm * xn
    }
    __syncthreads();
    {
        int h = t >> 8, d = t & 255;    // 4 quarters x 16 m's each
        float g = 0.f;
        #pragma unroll 4
        for (int mi = 0; mi < 16; ++mi) {
            int m = h * 16 + mi;
            g += csL[m] * bf2f(xn[((size_t)(b * Nn + c0 + m)) * Dn + d]);
        }
        gQ[h][d] = g;
    }
    __syncthreads();
    if (t < Dn)
        gpart[(b * 32 + ck) * Dn + t] = gQ[0][t] + gQ[1][t] + gQ[2][t] + gQ[3][t];
}

// ---- K4: reduce partials -> matvecs (4-way d-chunk parallel) -> LN -> out --

__global__ __launch_bounds__(1024) void k_final2(
    const float* __restrict__ gpart, const float* __restrict__ xpart,
    const float* __restrict__ W_rp, const float* __restrict__ b_rp,
    const float* __restrict__ W_gp, const float* __restrict__ b_gp,
    const float* __restrict__ gamma, const float* __restrict__ beta,
    float* __restrict__ out) {
    int b = blockIdx.x, t = threadIdx.x;
    const int d = t & 255, c4 = t >> 8;   // c4 in 0..3
    __shared__ float pS[4][Dn];           // partial buffer (reused)
    __shared__ float xS[4][Dn];
    __shared__ float gp_s[Dn];
    __shared__ float xm_s[Dn];
    __shared__ float g1_s[Dn];
    __shared__ float red[8];
    // fold gpart/xpart: each c4 sums 8 chunks
    {
        float gs = 0.f, xs = 0.f;
        #pragma unroll
        for (int k = 0; k < 8; ++k) {
            int ck = c4 * 8 + k;
            gs += gpart[(b * 32 + ck) * Dn + d];
            xs += xpart[(b * 32 + ck) * Dn + d];
        }
        pS[c4][d] = gs;
        xS[c4][d] = xs;
    }
    __syncthreads();
    if (t < Dn) {
        gp_s[t] = (pS[0][t] + pS[1][t] + pS[2][t] + pS[3][t]) * (1.0f / Nn);
        xm_s[t] = (xS[0][t] + xS[1][t] + xS[2][t] + xS[3][t]) * (1.0f / Nn);
    }
    __syncthreads();
    // matvec1: g1 = W_rp^T gp + b_rp, 4-way over d-chunks
    {
        float m1 = 0.f;
        #pragma unroll 4
        for (int i = 0; i < 64; ++i) {
            int dd = c4 * 64 + i;
            m1 += gp_s[dd] * W_rp[dd * Dn + d];
        }
        pS[c4][d] = m1;
    }
    __syncthreads();
    if (t < Dn) g1_s[t] = b_rp[t] + pS[0][t] + pS[1][t] + pS[2][t] + pS[3][t];
    __syncthreads();
    // matvec2: g2 = W_gp^T g1 + b_gp
    {
        float m2 = 0.f;
        #pragma unroll 4
        for (int i = 0; i < 64; ++i) {
            int ee = c4 * 64 + i;
            m2 += g1_s[ee] * W_gp[ee * Dn + d];
        }
        pS[c4][d] = m2;
    }
    __syncthreads();
    float h = 0.f;
    if (t < Dn) {
        h = b_gp[t] + pS[0][t] + pS[1][t] + pS[2][t] + pS[3][t] + xm_s[t];
        float sum = h;
        #pragma unroll
        for (int m = 1; m < 64; m <<= 1) sum += __shfl_xor(sum, m);
        if ((t & 63) == 0) red[t >> 6] = sum;
    }
    __syncthreads();
    float mu = (red[0] + red[1] + red[2] + red[3]) * (1.0f / Dn);
    if (t < Dn) {
        float dv = h - mu;
        float s2 = dv * dv;
        #pragma unroll
        for (int m = 1; m < 64; m <<= 1) s2 += __shfl_xor(s2, m);
        if ((t & 63) == 0) red[4 + (t >> 6)] = s2;
    }
    __syncthreads();
    if (t < Dn) {
        float dv = h - mu;
        float var = (red[4] + red[5] + red[6] + red[7]) * (1.0f / Dn);
        out[b * Dn + t] = dv * rsqrtf(var + 1e-5f) * gamma[t] + beta[t];
    }
}

// ---- launcher --------------------------------------------------------------

extern "C" void kernel_launch(void* const* d_in, const int* in_sizes, int n_in,
                              void* d_out, int out_size, void* d_ws, size_t ws_size,
                              hipStream_t stream) {
    const float* x     = (const float*)d_in[0];
    const float* W_fp  = (const float*)d_in[1];
    const float* b_fp  = (const float*)d_in[2];
    const float* w_s   = (const float*)d_in[3];
    const float* b_s   = (const float*)d_in[4];
    const float* W_rp  = (const float*)d_in[5];
    const float* b_rp  = (const float*)d_in[6];
    const float* W_gp  = (const float*)d_in[7];
    const float* b_gp  = (const float*)d_in[8];
    const float* gamma = (const float*)d_in[9];
    const float* beta  = (const float*)d_in[10];

    float* out = (float*)d_out;
    float* adj = out + Bn * Dn;   // outputs concatenated: out (B*D) then adj (B*N*N)

    char* ws = (char*)d_ws;
    short* xn     = (short*)(ws);                 // 8 MB
    short* Wt     = (short*)(ws + 8388608);       // 128 KB
    float* sdot   = (float*)(ws + 8519680);       // 64 KB
    float* nrm    = (float*)(ws + 8585216);       // 64 KB
    float* degp   = (float*)(ws + 8650752);       // 512 KB (8 batches x 8 cx x 2048)
    float* invdeg = (float*)(ws + 9175040);       // 64 KB  (8 x 2048)
    float* gpart  = (float*)(ws + 9699328);       // 256 KB
    float* xpart  = (float*)(ws + 9961472);       // 256 KB

    k_transpose<<<dim3(4, 4), 256, 0, stream>>>(W_fp, Wt);
    k_projxn<<<(Bn * Nn) / 64, 512, 0, stream>>>(x, Wt, b_fp, w_s, xn, sdot, nrm, xpart);
    k_sim<<<dim3(8, 16, 8), 512, 0, stream>>>(xn, sdot, b_s, adj, degp);
    k_deg<<<dim3(Bn, 8), 256, 0, stream>>>(degp, invdeg);
    k_colsum<<<dim3(Bn, 32), 1024, 0, stream>>>(adj, invdeg, xn, nrm, gpart);
    k_final2<<<Bn, 1024, 0, stream>>>(gpart, xpart, W_rp, b_rp, W_gp, b_gp, gamma, beta, out);
}